// Round 1
// baseline (15137.735 us; speedup 1.0000x reference)
//
#include <hip/hip_runtime.h>

#define D_IN 512
#define D_H 1024
#define D_OUT 32000
#define NB 64
#define NS 512

typedef __attribute__((ext_vector_type(8))) short short8;
typedef __attribute__((ext_vector_type(8))) __bf16 bf16x8;
typedef __attribute__((ext_vector_type(4))) float f32x4;

__device__ __forceinline__ unsigned short f2bf(float f) {
  unsigned int u = __float_as_uint(f);
  u += 0x7fffu + ((u >> 16) & 1u);
  return (unsigned short)(u >> 16);
}
__device__ __forceinline__ float bf2f(unsigned short s) {
  return __uint_as_float(((unsigned int)s) << 16);
}

__device__ __forceinline__ f32x4 mfma_bf16(short8 a, short8 b, f32x4 c) {
  return __builtin_amdgcn_mfma_f32_16x16x32_bf16(
      __builtin_bit_cast(bf16x8, a), __builtin_bit_cast(bf16x8, b), c, 0, 0, 0);
}

union HQ { unsigned long long q[2]; short8 s; };

// ---------------------------------------------------------------------------
// init: zero flags, write h0 (split hi/lo bf16) into exchange buffer 0
// hex layout: [group(4)][buf(2)][plane(2)][b(16)][k(1024)] bf16
// ---------------------------------------------------------------------------
__global__ __launch_bounds__(256) void rnn_init(const float* __restrict__ h0,
                                                unsigned short* __restrict__ hex,
                                                unsigned int* __restrict__ flags) {
  int idx = blockIdx.x * 256 + threadIdx.x;  // 0..65535
  int bg = idx >> 10;                        // global batch 0..63
  int k = idx & 1023;
  int g = bg >> 4, bl = bg & 15;
  float v = h0[idx];
  unsigned short hh = f2bf(v);
  unsigned short hl = f2bf(v - bf2f(hh));
  size_t base = ((size_t)(g * 2 + 0) * 2) * 16384 + (size_t)bl * 1024 + k;
  hex[base] = hh;            // hi plane
  hex[base + 16384] = hl;    // lo plane
  if (blockIdx.x == 0) flags[threadIdx.x] = 0u;  // 256 flags
}

// ---------------------------------------------------------------------------
// pack W_ih [512][1024] fp32 -> B-fragment layout, hi/lo bf16 planes
// pack[((nc*16 + kc)*64 + l)*8 + j] = W_ih[kc*32 + (l>>4)*8 + j][nc*16 + (l&15)]
// ---------------------------------------------------------------------------
__global__ __launch_bounds__(256) void rnn_pack_wih(const float* __restrict__ W_ih,
                                                    unsigned short* __restrict__ bhi,
                                                    unsigned short* __restrict__ blo) {
  int idx = blockIdx.x * 256 + threadIdx.x;  // 0..524287
  int j = idx & 7;
  int l = (idx >> 3) & 63;
  int kc = (idx >> 9) & 15;
  int nc = idx >> 13;
  int k = kc * 32 + ((l >> 4) << 3) + j;
  int n = nc * 16 + (l & 15);
  float v = W_ih[(size_t)k * D_H + n];
  unsigned short h = f2bf(v);
  bhi[idx] = h;
  blo[idx] = f2bf(v - bf2f(h));
}

// ---------------------------------------------------------------------------
// stage 1: xw[t*64+b][n] = embed[tokens[b][t]] @ W_ih + bias_hh   (bf16x3 MFMA)
// grid 8192 = 512 M-tiles x 16 N-tiles, 256 thr (4 waves), tile 64x64, K=512
// ---------------------------------------------------------------------------
__global__ __launch_bounds__(256) void rnn_stage1(const int* __restrict__ tokens,
                                                  const float* __restrict__ embed,
                                                  const unsigned short* __restrict__ bhi,
                                                  const unsigned short* __restrict__ blo,
                                                  const float* __restrict__ bias,
                                                  float* __restrict__ xw) {
  int bx = blockIdx.x;
  int mt = bx >> 4, nt = bx & 15;
  int tid = threadIdx.x;
  int w = tid >> 6, l = tid & 63;
  int q = l >> 4;

  int m = mt * 64 + w * 16 + (l & 15);  // A-operand row
  int b = m & 63, t = m >> 6;
  int tok = tokens[b * NS + t];
  const float* arow = embed + (size_t)tok * D_IN;

  f32x4 acc[4];
#pragma unroll
  for (int i = 0; i < 4; ++i) acc[i] = (f32x4){0.f, 0.f, 0.f, 0.f};

  for (int c = 0; c < 16; ++c) {
    const float* ap = arow + c * 32 + q * 8;
    float4 f0 = *(const float4*)ap;
    float4 f1 = *(const float4*)(ap + 4);
    float fa[8] = {f0.x, f0.y, f0.z, f0.w, f1.x, f1.y, f1.z, f1.w};
    short8 ahi, alo;
#pragma unroll
    for (int j = 0; j < 8; ++j) {
      unsigned short hh = f2bf(fa[j]);
      ahi[j] = (short)hh;
      alo[j] = (short)f2bf(fa[j] - bf2f(hh));
    }
#pragma unroll
    for (int ni = 0; ni < 4; ++ni) {
      int ncg = nt * 4 + ni;
      size_t boff = ((size_t)(ncg * 16 + c) * 64 + l) * 8;
      short8 bh = *(const short8*)(bhi + boff);
      short8 bl_ = *(const short8*)(blo + boff);
      acc[ni] = mfma_bf16(ahi, bh, acc[ni]);
      acc[ni] = mfma_bf16(alo, bh, acc[ni]);
      acc[ni] = mfma_bf16(ahi, bl_, acc[ni]);
    }
  }

#pragma unroll
  for (int ni = 0; ni < 4; ++ni) {
    int col = nt * 64 + ni * 16 + (l & 15);
    float bv = bias[col];
#pragma unroll
    for (int r = 0; r < 4; ++r) {
      int row = mt * 64 + w * 16 + q * 4 + r;  // D-layout row
      xw[(size_t)row * D_H + col] = acc[ni][r] + bv;
    }
  }
}

// ---------------------------------------------------------------------------
// stage 2: persistent recurrence. 256 WGs = 4 batch-groups x 64 j-tiles.
// W_hh slice (1024 x 16) resident in LDS as bf16 hi/lo. Flag-based group sync.
// ---------------------------------------------------------------------------
__global__ __launch_bounds__(256, 1) void rnn_recur(const float* __restrict__ xw,
                                                    const float* __restrict__ W_hh,
                                                    unsigned short* __restrict__ hex,
                                                    unsigned int* __restrict__ flags,
                                                    float* __restrict__ h_last) {
  __shared__ short Whi[16384];
  __shared__ short Wlo[16384];
  __shared__ float red[4][16][17];

  const int tid = threadIdx.x;
  const int bx = blockIdx.x;
  const int g = bx >> 6;     // batch group 0..3
  const int jt = bx & 63;    // j tile 0..63
  const int jcol0 = jt * 16;
  const int w = tid >> 6;
  const int l = tid & 63;
  const int q = l >> 4;
  const int b_lane = l & 15;

  // one-time: load + split W_hh slice into LDS in B-fragment order
  for (int v = tid; v < 16384; v += 256) {
    int j = v & 7;
    int ll = (v >> 3) & 63;
    int c = v >> 9;
    int k = c * 32 + ((ll >> 4) << 3) + j;
    int n = ll & 15;
    float wv = W_hh[(size_t)k * D_H + jcol0 + n];
    unsigned short hh = f2bf(wv);
    Whi[v] = (short)hh;
    Wlo[v] = (short)f2bf(wv - bf2f(hh));
  }
  __syncthreads();

  unsigned int* flg = flags + g * 64;

  for (int t = 1; t <= NS; ++t) {
    // wait for all of the group's step-(t-1) tiles
    if (tid < 64) {
      unsigned int target = (unsigned int)(t - 1);
      while (1) {
        unsigned int v = __hip_atomic_load(&flg[tid], __ATOMIC_RELAXED,
                                           __HIP_MEMORY_SCOPE_AGENT);
        if (__all((int)(v >= target))) break;
      }
    }
    __syncthreads();

    int rbuf = (t - 1) & 1;
    const unsigned long long* hhi =
        (const unsigned long long*)(hex + ((size_t)(g * 2 + rbuf) * 2 + 0) * 16384);
    const unsigned long long* hlo =
        (const unsigned long long*)(hex + ((size_t)(g * 2 + rbuf) * 2 + 1) * 16384);

    f32x4 acc0 = {0.f, 0.f, 0.f, 0.f};
    f32x4 acc1 = {0.f, 0.f, 0.f, 0.f};
    f32x4 acc2 = {0.f, 0.f, 0.f, 0.f};
#pragma unroll
    for (int i = 0; i < 8; ++i) {
      int c = w * 8 + i;
      int k = c * 32 + q * 8;
      size_t qi = ((size_t)b_lane * 1024 + k) >> 2;  // u64 index
      HQ ua, ul;
      ua.q[0] = __hip_atomic_load(hhi + qi, __ATOMIC_RELAXED, __HIP_MEMORY_SCOPE_AGENT);
      ua.q[1] = __hip_atomic_load(hhi + qi + 1, __ATOMIC_RELAXED, __HIP_MEMORY_SCOPE_AGENT);
      ul.q[0] = __hip_atomic_load(hlo + qi, __ATOMIC_RELAXED, __HIP_MEMORY_SCOPE_AGENT);
      ul.q[1] = __hip_atomic_load(hlo + qi + 1, __ATOMIC_RELAXED, __HIP_MEMORY_SCOPE_AGENT);
      short8 bh = *(const short8*)(Whi + c * 512 + l * 8);
      short8 bl_ = *(const short8*)(Wlo + c * 512 + l * 8);
      acc0 = mfma_bf16(ua.s, bh, acc0);
      acc1 = mfma_bf16(ul.s, bh, acc1);
      acc2 = mfma_bf16(ua.s, bl_, acc2);
    }
    f32x4 accs = acc0 + acc1 + acc2;
#pragma unroll
    for (int r = 0; r < 4; ++r) red[w][q * 4 + r][b_lane] = accs[r];
    __syncthreads();

    if (tid < 128) {
      int bl = tid >> 3;
      int jp = tid & 7;
      int j0 = jp * 2;
      int brow = g * 16 + bl;
      const float* xwp = xw + ((size_t)(t - 1) * 64 + brow) * D_H + jcol0 + j0;
      float z0 = red[0][bl][j0] + red[1][bl][j0] + red[2][bl][j0] + red[3][bl][j0] + xwp[0];
      float z1 = red[0][bl][j0 + 1] + red[1][bl][j0 + 1] + red[2][bl][j0 + 1] +
                 red[3][bl][j0 + 1] + xwp[1];
      float hv0 = tanhf(z0);
      float hv1 = tanhf(z1);
      unsigned short h0h = f2bf(hv0), h1h = f2bf(hv1);
      unsigned short h0l = f2bf(hv0 - bf2f(h0h)), h1l = f2bf(hv1 - bf2f(h1h));
      int wbuf = t & 1;
      size_t obase = (size_t)bl * 1024 + jcol0 + j0;
      unsigned int* dhi =
          (unsigned int*)(hex + ((size_t)(g * 2 + wbuf) * 2 + 0) * 16384 + obase);
      unsigned int* dlo =
          (unsigned int*)(hex + ((size_t)(g * 2 + wbuf) * 2 + 1) * 16384 + obase);
      unsigned int phi = (unsigned int)h0h | ((unsigned int)h1h << 16);
      unsigned int plo = (unsigned int)h0l | ((unsigned int)h1l << 16);
      __hip_atomic_store(dhi, phi, __ATOMIC_RELAXED, __HIP_MEMORY_SCOPE_AGENT);
      __hip_atomic_store(dlo, plo, __ATOMIC_RELAXED, __HIP_MEMORY_SCOPE_AGENT);
      if (t == NS) {
        h_last[(size_t)brow * 1024 + jcol0 + j0] = hv0;
        h_last[(size_t)brow * 1024 + jcol0 + j0 + 1] = hv1;
      }
    }
    __threadfence();   // release: drain h stores to the coherent point
    __syncthreads();   // all threads fenced before flag publication
    if (tid == 0)
      __hip_atomic_store(&flg[jt], (unsigned int)t, __ATOMIC_RELAXED,
                         __HIP_MEMORY_SCOPE_AGENT);
  }
}

// ---------------------------------------------------------------------------
// stage 3: y[b][j] = h_last[b][:] . W_out[:][j] + b_out[j]   (fp32 vector)
// grid 250 WGs x 256 thr; thread = (j_local 0..127, k_half 0..1), acc over 64 b
// ---------------------------------------------------------------------------
__global__ __launch_bounds__(256, 2) void rnn_out(const float* __restrict__ h_last,
                                                  const float* __restrict__ W_out,
                                                  const float* __restrict__ b_out,
                                                  float* __restrict__ out) {
  __shared__ float smem[16384];
  int tid = threadIdx.x;
  int jl = tid & 127;
  int kh = tid >> 7;
  int j = blockIdx.x * 128 + jl;

  float acc[64];
#pragma unroll
  for (int b = 0; b < 64; ++b) acc[b] = 0.f;

  for (int kc = 0; kc < 4; ++kc) {
    __syncthreads();
    for (int v = tid; v < 16384; v += 256) {
      int kh2 = v >> 13;
      int b = (v >> 7) & 63;
      int kk = v & 127;
      smem[v] = h_last[(size_t)b * 1024 + kh2 * 512 + kc * 128 + kk];
    }
    __syncthreads();
    int kbase = kh * 512 + kc * 128;
    for (int kkc = 0; kkc < 16; ++kkc) {
      float wreg[8];
#pragma unroll
      for (int i = 0; i < 8; ++i)
        wreg[i] = W_out[(size_t)(kbase + kkc * 8 + i) * D_OUT + j];
#pragma unroll
      for (int b = 0; b < 64; ++b) {
        const float* hp = &smem[kh * 8192 + b * 128 + kkc * 8];
#pragma unroll
        for (int i = 0; i < 8; ++i) acc[b] += hp[i] * wreg[i];
      }
    }
  }
  __syncthreads();
  if (kh == 1) {
#pragma unroll
    for (int b = 0; b < 64; ++b) smem[jl * 65 + b] = acc[b];
  }
  __syncthreads();
  if (kh == 0) {
    float bo = b_out[j];
#pragma unroll
    for (int b = 0; b < 64; ++b)
      out[(size_t)b * D_OUT + j] = acc[b] + smem[jl * 65 + b] + bo;
  }
}

// ---------------------------------------------------------------------------
extern "C" void kernel_launch(void* const* d_in, const int* in_sizes, int n_in,
                              void* d_out, int out_size, void* d_ws, size_t ws_size,
                              hipStream_t stream) {
  const int* tokens = (const int*)d_in[0];
  const float* h0 = (const float*)d_in[1];
  const float* embed = (const float*)d_in[2];
  const float* W_ih = (const float*)d_in[3];
  const float* W_hh = (const float*)d_in[4];
  const float* bias_hh = (const float*)d_in[5];
  const float* W_out = (const float*)d_in[6];
  const float* b_out = (const float*)d_in[7];
  float* out = (float*)d_out;

  char* ws = (char*)d_ws;
  // workspace layout (bytes)
  float* xw = (float*)(ws);                                   // 134217728
  unsigned short* wih_hi = (unsigned short*)(ws + 134217728); // 1048576
  unsigned short* wih_lo = (unsigned short*)(ws + 135266304); // 1048576
  unsigned short* hex = (unsigned short*)(ws + 136314880);    // 524288
  unsigned int* flags = (unsigned int*)(ws + 136839168);      // 1024
  float* h_last = (float*)(ws + 136840192);                   // 262144
  // total: 137102336 bytes

  rnn_init<<<256, 256, 0, stream>>>(h0, hex, flags);
  rnn_pack_wih<<<2048, 256, 0, stream>>>(W_ih, wih_hi, wih_lo);
  rnn_stage1<<<8192, 256, 0, stream>>>(tokens, embed, wih_hi, wih_lo, bias_hh, xw);
  rnn_recur<<<256, 256, 0, stream>>>(xw, W_hh, hex, flags, h_last);
  rnn_out<<<250, 256, 0, stream>>>(h_last, W_out, b_out, out);
}

// Round 2
// 4759.641 us; speedup vs baseline: 3.1804x; 3.1804x over previous
//
#include <hip/hip_runtime.h>

#define D_IN 512
#define D_H 1024
#define D_OUT 32000
#define NB 64
#define NS 512

typedef __attribute__((ext_vector_type(8))) short short8;
typedef __attribute__((ext_vector_type(8))) __bf16 bf16x8;
typedef __attribute__((ext_vector_type(4))) float f32x4;

__device__ __forceinline__ unsigned short f2bf(float f) {
  unsigned int u = __float_as_uint(f);
  u += 0x7fffu + ((u >> 16) & 1u);
  return (unsigned short)(u >> 16);
}
__device__ __forceinline__ float bf2f(unsigned short s) {
  return __uint_as_float(((unsigned int)s) << 16);
}

__device__ __forceinline__ f32x4 mfma_bf16(short8 a, short8 b, f32x4 c) {
  return __builtin_amdgcn_mfma_f32_16x16x32_bf16(
      __builtin_bit_cast(bf16x8, a), __builtin_bit_cast(bf16x8, b), c, 0, 0, 0);
}

union HQ { unsigned long long q[2]; short8 s; };

// ---------------------------------------------------------------------------
// init: zero flags, write h0 (split hi/lo bf16) into exchange buffer 0
// hex layout: [group(4)][buf(2)][plane(2)][b(16)][k(1024)] bf16
// ---------------------------------------------------------------------------
__global__ __launch_bounds__(256) void rnn_init(const float* __restrict__ h0,
                                                unsigned short* __restrict__ hex,
                                                unsigned int* __restrict__ flags) {
  int idx = blockIdx.x * 256 + threadIdx.x;  // 0..65535
  int bg = idx >> 10;                        // global batch 0..63
  int k = idx & 1023;
  int g = bg >> 4, bl = bg & 15;
  float v = h0[idx];
  unsigned short hh = f2bf(v);
  unsigned short hl = f2bf(v - bf2f(hh));
  size_t base = ((size_t)(g * 2 + 0) * 2) * 16384 + (size_t)bl * 1024 + k;
  hex[base] = hh;            // hi plane
  hex[base + 16384] = hl;    // lo plane
  if (blockIdx.x == 0) flags[threadIdx.x] = 0u;  // 256 flags
}

// ---------------------------------------------------------------------------
// pack W_ih [512][1024] fp32 -> B-fragment layout, hi/lo bf16 planes
// ---------------------------------------------------------------------------
__global__ __launch_bounds__(256) void rnn_pack_wih(const float* __restrict__ W_ih,
                                                    unsigned short* __restrict__ bhi,
                                                    unsigned short* __restrict__ blo) {
  int idx = blockIdx.x * 256 + threadIdx.x;  // 0..524287
  int j = idx & 7;
  int l = (idx >> 3) & 63;
  int kc = (idx >> 9) & 15;
  int nc = idx >> 13;
  int k = kc * 32 + ((l >> 4) << 3) + j;
  int n = nc * 16 + (l & 15);
  float v = W_ih[(size_t)k * D_H + n];
  unsigned short h = f2bf(v);
  bhi[idx] = h;
  blo[idx] = f2bf(v - bf2f(h));
}

// ---------------------------------------------------------------------------
// stage 1: xw[t*64+b][n] = embed[tokens[b][t]] @ W_ih + bias_hh   (bf16x3 MFMA)
// ---------------------------------------------------------------------------
__global__ __launch_bounds__(256) void rnn_stage1(const int* __restrict__ tokens,
                                                  const float* __restrict__ embed,
                                                  const unsigned short* __restrict__ bhi,
                                                  const unsigned short* __restrict__ blo,
                                                  const float* __restrict__ bias,
                                                  float* __restrict__ xw) {
  int bx = blockIdx.x;
  int mt = bx >> 4, nt = bx & 15;
  int tid = threadIdx.x;
  int w = tid >> 6, l = tid & 63;
  int q = l >> 4;

  int m = mt * 64 + w * 16 + (l & 15);  // A-operand row
  int b = m & 63, t = m >> 6;
  int tok = tokens[b * NS + t];
  const float* arow = embed + (size_t)tok * D_IN;

  f32x4 acc[4];
#pragma unroll
  for (int i = 0; i < 4; ++i) acc[i] = (f32x4){0.f, 0.f, 0.f, 0.f};

  for (int c = 0; c < 16; ++c) {
    const float* ap = arow + c * 32 + q * 8;
    float4 f0 = *(const float4*)ap;
    float4 f1 = *(const float4*)(ap + 4);
    float fa[8] = {f0.x, f0.y, f0.z, f0.w, f1.x, f1.y, f1.z, f1.w};
    short8 ahi, alo;
#pragma unroll
    for (int j = 0; j < 8; ++j) {
      unsigned short hh = f2bf(fa[j]);
      ahi[j] = (short)hh;
      alo[j] = (short)f2bf(fa[j] - bf2f(hh));
    }
#pragma unroll
    for (int ni = 0; ni < 4; ++ni) {
      int ncg = nt * 4 + ni;
      size_t boff = ((size_t)(ncg * 16 + c) * 64 + l) * 8;
      short8 bh = *(const short8*)(bhi + boff);
      short8 bl_ = *(const short8*)(blo + boff);
      acc[ni] = mfma_bf16(ahi, bh, acc[ni]);
      acc[ni] = mfma_bf16(alo, bh, acc[ni]);
      acc[ni] = mfma_bf16(ahi, bl_, acc[ni]);
    }
  }

#pragma unroll
  for (int ni = 0; ni < 4; ++ni) {
    int col = nt * 64 + ni * 16 + (l & 15);
    float bv = bias[col];
#pragma unroll
    for (int r = 0; r < 4; ++r) {
      int row = mt * 64 + w * 16 + q * 4 + r;  // D-layout row
      xw[(size_t)row * D_H + col] = acc[ni][r] + bv;
    }
  }
}

// ---------------------------------------------------------------------------
// stage 2: persistent recurrence. 256 WGs = 4 batch-groups x 64 j-tiles.
// W_hh slice (1024 x 16) resident in LDS as bf16 hi/lo. Flag-based group sync.
// All cross-WG traffic uses agent-scope atomics (sc1 write-through), so the
// release is just s_waitcnt vmcnt(0) — NO __threadfence (avoids per-step
// buffer_wbl2/buffer_inv L2 maintenance, the round-1 bottleneck theory).
// ---------------------------------------------------------------------------
__global__ __launch_bounds__(256, 1) void rnn_recur(const float* __restrict__ xw,
                                                    const float* __restrict__ W_hh,
                                                    unsigned short* __restrict__ hex,
                                                    unsigned int* __restrict__ flags,
                                                    float* __restrict__ h_last) {
  __shared__ short Whi[16384];
  __shared__ short Wlo[16384];
  __shared__ float red[4][16][17];

  const int tid = threadIdx.x;
  const int bx = blockIdx.x;
  const int g = bx >> 6;     // batch group 0..3
  const int jt = bx & 63;    // j tile 0..63
  const int jcol0 = jt * 16;
  const int w = tid >> 6;
  const int l = tid & 63;
  const int q = l >> 4;
  const int b_lane = l & 15;

  // one-time: load + split W_hh slice into LDS in B-fragment order
  for (int v = tid; v < 16384; v += 256) {
    int j = v & 7;
    int ll = (v >> 3) & 63;
    int c = v >> 9;
    int k = c * 32 + ((ll >> 4) << 3) + j;
    int n = ll & 15;
    float wv = W_hh[(size_t)k * D_H + jcol0 + n];
    unsigned short hh = f2bf(wv);
    Whi[v] = (short)hh;
    Wlo[v] = (short)f2bf(wv - bf2f(hh));
  }
  __syncthreads();

  unsigned int* flg = flags + g * 64;

  // per-thread epilogue constants (tid<128 path)
  const int bl_e = tid >> 3;
  const int j0_e = (tid & 7) * 2;
  const int brow_e = g * 16 + bl_e;

  for (int t = 1; t <= NS; ++t) {
    // prefetch this step's xw contribution (flag-independent; hides under poll)
    float xv0 = 0.f, xv1 = 0.f;
    if (tid < 128) {
      const float* xwp = xw + ((size_t)(t - 1) * 64 + brow_e) * D_H + jcol0 + j0_e;
      xv0 = xwp[0];
      xv1 = xwp[1];
    }

    // wait for all of the group's step-(t-1) tiles
    if (tid < 64) {
      unsigned int target = (unsigned int)(t - 1);
      while (1) {
        unsigned int v = __hip_atomic_load(&flg[tid], __ATOMIC_RELAXED,
                                           __HIP_MEMORY_SCOPE_AGENT);
        if (__all((int)(v >= target))) break;
      }
    }
    __syncthreads();

    int rbuf = (t - 1) & 1;
    const unsigned long long* hhi =
        (const unsigned long long*)(hex + ((size_t)(g * 2 + rbuf) * 2 + 0) * 16384);
    const unsigned long long* hlo =
        (const unsigned long long*)(hex + ((size_t)(g * 2 + rbuf) * 2 + 1) * 16384);

    f32x4 acc0 = {0.f, 0.f, 0.f, 0.f};
    f32x4 acc1 = {0.f, 0.f, 0.f, 0.f};
    f32x4 acc2 = {0.f, 0.f, 0.f, 0.f};
#pragma unroll
    for (int i = 0; i < 8; ++i) {
      int c = w * 8 + i;
      int k = c * 32 + q * 8;
      size_t qi = ((size_t)b_lane * 1024 + k) >> 2;  // u64 index
      HQ ua, ul;
      ua.q[0] = __hip_atomic_load(hhi + qi, __ATOMIC_RELAXED, __HIP_MEMORY_SCOPE_AGENT);
      ua.q[1] = __hip_atomic_load(hhi + qi + 1, __ATOMIC_RELAXED, __HIP_MEMORY_SCOPE_AGENT);
      ul.q[0] = __hip_atomic_load(hlo + qi, __ATOMIC_RELAXED, __HIP_MEMORY_SCOPE_AGENT);
      ul.q[1] = __hip_atomic_load(hlo + qi + 1, __ATOMIC_RELAXED, __HIP_MEMORY_SCOPE_AGENT);
      short8 bh = *(const short8*)(Whi + c * 512 + l * 8);
      short8 bl_ = *(const short8*)(Wlo + c * 512 + l * 8);
      acc0 = mfma_bf16(ua.s, bh, acc0);
      acc1 = mfma_bf16(ul.s, bh, acc1);
      acc2 = mfma_bf16(ua.s, bl_, acc2);
    }
    f32x4 accs = acc0 + acc1 + acc2;
#pragma unroll
    for (int r = 0; r < 4; ++r) red[w][q * 4 + r][b_lane] = accs[r];
    __syncthreads();

    if (tid < 128) {
      float z0 = red[0][bl_e][j0_e] + red[1][bl_e][j0_e] + red[2][bl_e][j0_e] +
                 red[3][bl_e][j0_e] + xv0;
      float z1 = red[0][bl_e][j0_e + 1] + red[1][bl_e][j0_e + 1] +
                 red[2][bl_e][j0_e + 1] + red[3][bl_e][j0_e + 1] + xv1;
      float hv0 = tanhf(z0);
      float hv1 = tanhf(z1);
      unsigned short h0h = f2bf(hv0), h1h = f2bf(hv1);
      unsigned short h0l = f2bf(hv0 - bf2f(h0h)), h1l = f2bf(hv1 - bf2f(h1h));
      int wbuf = t & 1;
      size_t obase = (size_t)bl_e * 1024 + jcol0 + j0_e;
      unsigned int* dhi =
          (unsigned int*)(hex + ((size_t)(g * 2 + wbuf) * 2 + 0) * 16384 + obase);
      unsigned int* dlo =
          (unsigned int*)(hex + ((size_t)(g * 2 + wbuf) * 2 + 1) * 16384 + obase);
      unsigned int phi = (unsigned int)h0h | ((unsigned int)h1h << 16);
      unsigned int plo = (unsigned int)h0l | ((unsigned int)h1l << 16);
      __hip_atomic_store(dhi, phi, __ATOMIC_RELAXED, __HIP_MEMORY_SCOPE_AGENT);
      __hip_atomic_store(dlo, plo, __ATOMIC_RELAXED, __HIP_MEMORY_SCOPE_AGENT);
      if (t == NS) {
        h_last[(size_t)brow_e * 1024 + jcol0 + j0_e] = hv0;
        h_last[(size_t)brow_e * 1024 + jcol0 + j0_e + 1] = hv1;
      }
    }
    // Release: drain this wave's sc1 write-through stores to the LLC.
    // (sc1 atomics are visible at the coherence point once vmcnt==0 —
    //  no L2 writeback/invalidate needed, unlike __threadfence().)
    asm volatile("s_waitcnt vmcnt(0)" ::: "memory");
    __syncthreads();   // all waves drained before flag publication
    if (tid == 0)
      __hip_atomic_store(&flg[jt], (unsigned int)t, __ATOMIC_RELAXED,
                         __HIP_MEMORY_SCOPE_AGENT);
  }
}

// ---------------------------------------------------------------------------
// stage 3: y[b][j] = h_last[b][:] . W_out[:][j] + b_out[j]   (fp32 vector)
// ---------------------------------------------------------------------------
__global__ __launch_bounds__(256, 2) void rnn_out(const float* __restrict__ h_last,
                                                  const float* __restrict__ W_out,
                                                  const float* __restrict__ b_out,
                                                  float* __restrict__ out) {
  __shared__ float smem[16384];
  int tid = threadIdx.x;
  int jl = tid & 127;
  int kh = tid >> 7;
  int j = blockIdx.x * 128 + jl;

  float acc[64];
#pragma unroll
  for (int b = 0; b < 64; ++b) acc[b] = 0.f;

  for (int kc = 0; kc < 4; ++kc) {
    __syncthreads();
    for (int v = tid; v < 16384; v += 256) {
      int kh2 = v >> 13;
      int b = (v >> 7) & 63;
      int kk = v & 127;
      smem[v] = h_last[(size_t)b * 1024 + kh2 * 512 + kc * 128 + kk];
    }
    __syncthreads();
    int kbase = kh * 512 + kc * 128;
    for (int kkc = 0; kkc < 16; ++kkc) {
      float wreg[8];
#pragma unroll
      for (int i = 0; i < 8; ++i)
        wreg[i] = W_out[(size_t)(kbase + kkc * 8 + i) * D_OUT + j];
#pragma unroll
      for (int b = 0; b < 64; ++b) {
        const float* hp = &smem[kh * 8192 + b * 128 + kkc * 8];
#pragma unroll
        for (int i = 0; i < 8; ++i) acc[b] += hp[i] * wreg[i];
      }
    }
  }
  __syncthreads();
  if (kh == 1) {
#pragma unroll
    for (int b = 0; b < 64; ++b) smem[jl * 65 + b] = acc[b];
  }
  __syncthreads();
  if (kh == 0) {
    float bo = b_out[j];
#pragma unroll
    for (int b = 0; b < 64; ++b)
      out[(size_t)b * D_OUT + j] = acc[b] + smem[jl * 65 + b] + bo;
  }
}

// ---------------------------------------------------------------------------
extern "C" void kernel_launch(void* const* d_in, const int* in_sizes, int n_in,
                              void* d_out, int out_size, void* d_ws, size_t ws_size,
                              hipStream_t stream) {
  const int* tokens = (const int*)d_in[0];
  const float* h0 = (const float*)d_in[1];
  const float* embed = (const float*)d_in[2];
  const float* W_ih = (const float*)d_in[3];
  const float* W_hh = (const float*)d_in[4];
  const float* bias_hh = (const float*)d_in[5];
  const float* W_out = (const float*)d_in[6];
  const float* b_out = (const float*)d_in[7];
  float* out = (float*)d_out;

  char* ws = (char*)d_ws;
  // workspace layout (bytes)
  float* xw = (float*)(ws);                                   // 134217728
  unsigned short* wih_hi = (unsigned short*)(ws + 134217728); // 1048576
  unsigned short* wih_lo = (unsigned short*)(ws + 135266304); // 1048576
  unsigned short* hex = (unsigned short*)(ws + 136314880);    // 524288
  unsigned int* flags = (unsigned int*)(ws + 136839168);      // 1024
  float* h_last = (float*)(ws + 136840192);                   // 262144
  // total: 137102336 bytes

  rnn_init<<<256, 256, 0, stream>>>(h0, hex, flags);
  rnn_pack_wih<<<2048, 256, 0, stream>>>(W_ih, wih_hi, wih_lo);
  rnn_stage1<<<8192, 256, 0, stream>>>(tokens, embed, wih_hi, wih_lo, bias_hh, xw);
  rnn_recur<<<256, 256, 0, stream>>>(xw, W_hh, hex, flags, h_last);
  rnn_out<<<250, 256, 0, stream>>>(h_last, W_out, b_out, out);
}

// Round 3
// 3686.867 us; speedup vs baseline: 4.1059x; 1.2910x over previous
//
#include <hip/hip_runtime.h>

#define D_IN 512
#define D_H 1024
#define D_OUT 32000
#define NB 64
#define NS 512

typedef __attribute__((ext_vector_type(8))) short short8;
typedef __attribute__((ext_vector_type(8))) __bf16 bf16x8;
typedef __attribute__((ext_vector_type(4))) float f32x4;

__device__ __forceinline__ unsigned short f2bf(float f) {
  unsigned int u = __float_as_uint(f);
  u += 0x7fffu + ((u >> 16) & 1u);
  return (unsigned short)(u >> 16);
}
__device__ __forceinline__ float bf2f(unsigned short s) {
  return __uint_as_float(((unsigned int)s) << 16);
}

__device__ __forceinline__ f32x4 mfma_bf16(short8 a, short8 b, f32x4 c) {
  return __builtin_amdgcn_mfma_f32_16x16x32_bf16(
      __builtin_bit_cast(bf16x8, a), __builtin_bit_cast(bf16x8, b), c, 0, 0, 0);
}

union HQ { unsigned long long q[2]; short8 s; };

// ---------------------------------------------------------------------------
// init: zero counters, write h0 (split hi/lo bf16) into exchange buffer 0
// hex layout: [group(4)][buf(2)][plane(2)][b(16)][k(1024)] bf16
// ---------------------------------------------------------------------------
__global__ __launch_bounds__(256) void rnn_init(const float* __restrict__ h0,
                                                unsigned short* __restrict__ hex,
                                                unsigned int* __restrict__ flags) {
  int idx = blockIdx.x * 256 + threadIdx.x;  // 0..65535
  int bg = idx >> 10;                        // global batch 0..63
  int k = idx & 1023;
  int g = bg >> 4, bl = bg & 15;
  float v = h0[idx];
  unsigned short hh = f2bf(v);
  unsigned short hl = f2bf(v - bf2f(hh));
  size_t base = ((size_t)(g * 2 + 0) * 2) * 16384 + (size_t)bl * 1024 + k;
  hex[base] = hh;            // hi plane
  hex[base + 16384] = hl;    // lo plane
  if (blockIdx.x == 0) flags[threadIdx.x] = 0u;  // counters at flags[g*64]
}

// ---------------------------------------------------------------------------
// pack W_ih [512][1024] fp32 -> B-fragment layout, hi/lo bf16 planes
// ---------------------------------------------------------------------------
__global__ __launch_bounds__(256) void rnn_pack_wih(const float* __restrict__ W_ih,
                                                    unsigned short* __restrict__ bhi,
                                                    unsigned short* __restrict__ blo) {
  int idx = blockIdx.x * 256 + threadIdx.x;  // 0..524287
  int j = idx & 7;
  int l = (idx >> 3) & 63;
  int kc = (idx >> 9) & 15;
  int nc = idx >> 13;
  int k = kc * 32 + ((l >> 4) << 3) + j;
  int n = nc * 16 + (l & 15);
  float v = W_ih[(size_t)k * D_H + n];
  unsigned short h = f2bf(v);
  bhi[idx] = h;
  blo[idx] = f2bf(v - bf2f(h));
}

// ---------------------------------------------------------------------------
// stage 1: xw[t*64+b][n] = embed[tokens[b][t]] @ W_ih + bias_hh   (bf16x3 MFMA)
// ---------------------------------------------------------------------------
__global__ __launch_bounds__(256) void rnn_stage1(const int* __restrict__ tokens,
                                                  const float* __restrict__ embed,
                                                  const unsigned short* __restrict__ bhi,
                                                  const unsigned short* __restrict__ blo,
                                                  const float* __restrict__ bias,
                                                  float* __restrict__ xw) {
  int bx = blockIdx.x;
  int mt = bx >> 4, nt = bx & 15;
  int tid = threadIdx.x;
  int w = tid >> 6, l = tid & 63;
  int q = l >> 4;

  int m = mt * 64 + w * 16 + (l & 15);  // A-operand row
  int b = m & 63, t = m >> 6;
  int tok = tokens[b * NS + t];
  const float* arow = embed + (size_t)tok * D_IN;

  f32x4 acc[4];
#pragma unroll
  for (int i = 0; i < 4; ++i) acc[i] = (f32x4){0.f, 0.f, 0.f, 0.f};

  for (int c = 0; c < 16; ++c) {
    const float* ap = arow + c * 32 + q * 8;
    float4 f0 = *(const float4*)ap;
    float4 f1 = *(const float4*)(ap + 4);
    float fa[8] = {f0.x, f0.y, f0.z, f0.w, f1.x, f1.y, f1.z, f1.w};
    short8 ahi, alo;
#pragma unroll
    for (int j = 0; j < 8; ++j) {
      unsigned short hh = f2bf(fa[j]);
      ahi[j] = (short)hh;
      alo[j] = (short)f2bf(fa[j] - bf2f(hh));
    }
#pragma unroll
    for (int ni = 0; ni < 4; ++ni) {
      int ncg = nt * 4 + ni;
      size_t boff = ((size_t)(ncg * 16 + c) * 64 + l) * 8;
      short8 bh = *(const short8*)(bhi + boff);
      short8 bl_ = *(const short8*)(blo + boff);
      acc[ni] = mfma_bf16(ahi, bh, acc[ni]);
      acc[ni] = mfma_bf16(alo, bh, acc[ni]);
      acc[ni] = mfma_bf16(ahi, bl_, acc[ni]);
    }
  }

#pragma unroll
  for (int ni = 0; ni < 4; ++ni) {
    int col = nt * 64 + ni * 16 + (l & 15);
    float bv = bias[col];
#pragma unroll
    for (int r = 0; r < 4; ++r) {
      int row = mt * 64 + w * 16 + q * 4 + r;  // D-layout row
      xw[(size_t)row * D_H + col] = acc[ni][r] + bv;
    }
  }
}

// ---------------------------------------------------------------------------
// stage 2: persistent recurrence. 256 WGs = 4 batch-groups x 64 j-tiles.
// W_hh slice (1024 x 16) resident in LDS as bf16 hi/lo.
// Sync: one arrival counter per group (atomicAdd publish, same-address poll).
// All h loads issued BEFORE the MFMA chain -> one pipelined LLC round
// instead of 8 serialized load->wait->mfma rounds (round-3 theory).
// ---------------------------------------------------------------------------
__global__ __launch_bounds__(256, 1) void rnn_recur(const float* __restrict__ xw,
                                                    const float* __restrict__ W_hh,
                                                    unsigned short* __restrict__ hex,
                                                    unsigned int* __restrict__ flags,
                                                    float* __restrict__ h_last) {
  __shared__ short Whi[16384];
  __shared__ short Wlo[16384];
  __shared__ float red[4][16][17];

  const int tid = threadIdx.x;
  const int bx = blockIdx.x;
  const int g = bx >> 6;     // batch group 0..3
  const int jt = bx & 63;    // j tile 0..63
  const int jcol0 = jt * 16;
  const int w = tid >> 6;
  const int l = tid & 63;
  const int q = l >> 4;
  const int b_lane = l & 15;

  // one-time: load + split W_hh slice into LDS in B-fragment order
  for (int v = tid; v < 16384; v += 256) {
    int j = v & 7;
    int ll = (v >> 3) & 63;
    int c = v >> 9;
    int k = c * 32 + ((ll >> 4) << 3) + j;
    int n = ll & 15;
    float wv = W_hh[(size_t)k * D_H + jcol0 + n];
    unsigned short hh = f2bf(wv);
    Whi[v] = (short)hh;
    Wlo[v] = (short)f2bf(wv - bf2f(hh));
  }
  __syncthreads();

  unsigned int* cnt = flags + g * 64;  // per-group arrival counter (256B apart)

  // per-thread epilogue constants (tid<128 path)
  const int bl_e = tid >> 3;
  const int j0_e = (tid & 7) * 2;
  const int brow_e = g * 16 + bl_e;

  for (int t = 1; t <= NS; ++t) {
    // prefetch this step's xw contribution (flag-independent; hides under poll)
    float xv0 = 0.f, xv1 = 0.f;
    if (tid < 128) {
      const float* xwp = xw + ((size_t)(t - 1) * 64 + brow_e) * D_H + jcol0 + j0_e;
      xv0 = xwp[0];
      xv1 = xwp[1];
    }

    // wait for all 64 of the group's step-(t-1) publications.
    // All lanes poll the SAME dword -> one coalesced LLC request per poll.
    // Each wave proceeds independently once it observes the count (no barrier).
    {
      unsigned int target = 64u * (unsigned int)(t - 1);
      while (__hip_atomic_load(cnt, __ATOMIC_RELAXED, __HIP_MEMORY_SCOPE_AGENT) <
             target) {
      }
    }

    int rbuf = (t - 1) & 1;
    const unsigned long long* hhi =
        (const unsigned long long*)(hex + ((size_t)(g * 2 + rbuf) * 2 + 0) * 16384);
    const unsigned long long* hlo =
        (const unsigned long long*)(hex + ((size_t)(g * 2 + rbuf) * 2 + 1) * 16384);

    // ---- issue ALL h loads first (one pipelined LLC round) ----
    HQ ha[8], hl_[8];
#pragma unroll
    for (int i = 0; i < 8; ++i) {
      int c = w * 8 + i;
      int k = c * 32 + q * 8;
      size_t qi = ((size_t)b_lane * 1024 + k) >> 2;  // u64 index
      ha[i].q[0] = __hip_atomic_load(hhi + qi, __ATOMIC_RELAXED, __HIP_MEMORY_SCOPE_AGENT);
      ha[i].q[1] = __hip_atomic_load(hhi + qi + 1, __ATOMIC_RELAXED, __HIP_MEMORY_SCOPE_AGENT);
      hl_[i].q[0] = __hip_atomic_load(hlo + qi, __ATOMIC_RELAXED, __HIP_MEMORY_SCOPE_AGENT);
      hl_[i].q[1] = __hip_atomic_load(hlo + qi + 1, __ATOMIC_RELAXED, __HIP_MEMORY_SCOPE_AGENT);
    }

    // ---- MFMA chain ----
    f32x4 acc0 = {0.f, 0.f, 0.f, 0.f};
    f32x4 acc1 = {0.f, 0.f, 0.f, 0.f};
    f32x4 acc2 = {0.f, 0.f, 0.f, 0.f};
#pragma unroll
    for (int i = 0; i < 8; ++i) {
      int c = w * 8 + i;
      short8 bh = *(const short8*)(Whi + c * 512 + l * 8);
      short8 bl_ = *(const short8*)(Wlo + c * 512 + l * 8);
      acc0 = mfma_bf16(ha[i].s, bh, acc0);
      acc1 = mfma_bf16(hl_[i].s, bh, acc1);
      acc2 = mfma_bf16(ha[i].s, bl_, acc2);
    }
    f32x4 accs = acc0 + acc1 + acc2;
#pragma unroll
    for (int r = 0; r < 4; ++r) red[w][q * 4 + r][b_lane] = accs[r];
    __syncthreads();

    if (tid < 128) {
      float z0 = red[0][bl_e][j0_e] + red[1][bl_e][j0_e] + red[2][bl_e][j0_e] +
                 red[3][bl_e][j0_e] + xv0;
      float z1 = red[0][bl_e][j0_e + 1] + red[1][bl_e][j0_e + 1] +
                 red[2][bl_e][j0_e + 1] + red[3][bl_e][j0_e + 1] + xv1;
      float hv0 = tanhf(z0);
      float hv1 = tanhf(z1);
      unsigned short h0h = f2bf(hv0), h1h = f2bf(hv1);
      unsigned short h0l = f2bf(hv0 - bf2f(h0h)), h1l = f2bf(hv1 - bf2f(h1h));
      int wbuf = t & 1;
      size_t obase = (size_t)bl_e * 1024 + jcol0 + j0_e;
      unsigned int* dhi =
          (unsigned int*)(hex + ((size_t)(g * 2 + wbuf) * 2 + 0) * 16384 + obase);
      unsigned int* dlo =
          (unsigned int*)(hex + ((size_t)(g * 2 + wbuf) * 2 + 1) * 16384 + obase);
      unsigned int phi = (unsigned int)h0h | ((unsigned int)h1h << 16);
      unsigned int plo = (unsigned int)h0l | ((unsigned int)h1l << 16);
      __hip_atomic_store(dhi, phi, __ATOMIC_RELAXED, __HIP_MEMORY_SCOPE_AGENT);
      __hip_atomic_store(dlo, plo, __ATOMIC_RELAXED, __HIP_MEMORY_SCOPE_AGENT);
      if (t == NS) {
        h_last[(size_t)brow_e * 1024 + jcol0 + j0_e] = hv0;
        h_last[(size_t)brow_e * 1024 + jcol0 + j0_e + 1] = hv1;
      }
    }
    // Release: drain this wave's sc1 write-through stores to the LLC,
    // then one arrival per WG. (Barrier also protects `red` reuse.)
    asm volatile("s_waitcnt vmcnt(0)" ::: "memory");
    __syncthreads();
    if (tid == 0)
      __hip_atomic_fetch_add(cnt, 1u, __ATOMIC_RELAXED, __HIP_MEMORY_SCOPE_AGENT);
  }
}

// ---------------------------------------------------------------------------
// stage 3: y[b][j] = h_last[b][:] . W_out[:][j] + b_out[j]   (fp32 vector)
// ---------------------------------------------------------------------------
__global__ __launch_bounds__(256, 2) void rnn_out(const float* __restrict__ h_last,
                                                  const float* __restrict__ W_out,
                                                  const float* __restrict__ b_out,
                                                  float* __restrict__ out) {
  __shared__ float smem[16384];
  int tid = threadIdx.x;
  int jl = tid & 127;
  int kh = tid >> 7;
  int j = blockIdx.x * 128 + jl;

  float acc[64];
#pragma unroll
  for (int b = 0; b < 64; ++b) acc[b] = 0.f;

  for (int kc = 0; kc < 4; ++kc) {
    __syncthreads();
    for (int v = tid; v < 16384; v += 256) {
      int kh2 = v >> 13;
      int b = (v >> 7) & 63;
      int kk = v & 127;
      smem[v] = h_last[(size_t)b * 1024 + kh2 * 512 + kc * 128 + kk];
    }
    __syncthreads();
    int kbase = kh * 512 + kc * 128;
    for (int kkc = 0; kkc < 16; ++kkc) {
      float wreg[8];
#pragma unroll
      for (int i = 0; i < 8; ++i)
        wreg[i] = W_out[(size_t)(kbase + kkc * 8 + i) * D_OUT + j];
#pragma unroll
      for (int b = 0; b < 64; ++b) {
        const float* hp = &smem[kh * 8192 + b * 128 + kkc * 8];
#pragma unroll
        for (int i = 0; i < 8; ++i) acc[b] += hp[i] * wreg[i];
      }
    }
  }
  __syncthreads();
  if (kh == 1) {
#pragma unroll
    for (int b = 0; b < 64; ++b) smem[jl * 65 + b] = acc[b];
  }
  __syncthreads();
  if (kh == 0) {
    float bo = b_out[j];
#pragma unroll
    for (int b = 0; b < 64; ++b)
      out[(size_t)b * D_OUT + j] = acc[b] + smem[jl * 65 + b] + bo;
  }
}

// ---------------------------------------------------------------------------
extern "C" void kernel_launch(void* const* d_in, const int* in_sizes, int n_in,
                              void* d_out, int out_size, void* d_ws, size_t ws_size,
                              hipStream_t stream) {
  const int* tokens = (const int*)d_in[0];
  const float* h0 = (const float*)d_in[1];
  const float* embed = (const float*)d_in[2];
  const float* W_ih = (const float*)d_in[3];
  const float* W_hh = (const float*)d_in[4];
  const float* bias_hh = (const float*)d_in[5];
  const float* W_out = (const float*)d_in[6];
  const float* b_out = (const float*)d_in[7];
  float* out = (float*)d_out;

  char* ws = (char*)d_ws;
  // workspace layout (bytes)
  float* xw = (float*)(ws);                                   // 134217728
  unsigned short* wih_hi = (unsigned short*)(ws + 134217728); // 1048576
  unsigned short* wih_lo = (unsigned short*)(ws + 135266304); // 1048576
  unsigned short* hex = (unsigned short*)(ws + 136314880);    // 524288
  unsigned int* flags = (unsigned int*)(ws + 136839168);      // 1024
  float* h_last = (float*)(ws + 136840192);                   // 262144
  // total: 137102336 bytes

  rnn_init<<<256, 256, 0, stream>>>(h0, hex, flags);
  rnn_pack_wih<<<2048, 256, 0, stream>>>(W_ih, wih_hi, wih_lo);
  rnn_stage1<<<8192, 256, 0, stream>>>(tokens, embed, wih_hi, wih_lo, bias_hh, xw);
  rnn_recur<<<256, 256, 0, stream>>>(xw, W_hh, hex, flags, h_last);
  rnn_out<<<250, 256, 0, stream>>>(h_last, W_out, b_out, out);
}

// Round 4
// 3600.352 us; speedup vs baseline: 4.2045x; 1.0240x over previous
//
#include <hip/hip_runtime.h>

#define D_IN 512
#define D_H 1024
#define D_OUT 32000
#define NB 64
#define NS 512

typedef __attribute__((ext_vector_type(8))) short short8;
typedef __attribute__((ext_vector_type(8))) __bf16 bf16x8;
typedef __attribute__((ext_vector_type(4))) float f32x4;

__device__ __forceinline__ unsigned short f2bf(float f) {
  unsigned int u = __float_as_uint(f);
  u += 0x7fffu + ((u >> 16) & 1u);
  return (unsigned short)(u >> 16);
}
__device__ __forceinline__ float bf2f(unsigned short s) {
  return __uint_as_float(((unsigned int)s) << 16);
}

__device__ __forceinline__ f32x4 mfma_bf16(short8 a, short8 b, f32x4 c) {
  return __builtin_amdgcn_mfma_f32_16x16x32_bf16(
      __builtin_bit_cast(bf16x8, a), __builtin_bit_cast(bf16x8, b), c, 0, 0, 0);
}

union HQ { unsigned long long q[2]; short8 s; };

// ---------------------------------------------------------------------------
// init: zero flags, write h0 (split hi/lo bf16) into exchange buffer 0
// hex layout: [group(4)][buf(2)][plane(2)][b(16)][k(1024)] bf16
// flags: group g's 32 per-WG flags at flags[g*32 .. g*32+31] (one 128B line)
// ---------------------------------------------------------------------------
__global__ __launch_bounds__(256) void rnn_init(const float* __restrict__ h0,
                                                unsigned short* __restrict__ hex,
                                                unsigned int* __restrict__ flags) {
  int idx = blockIdx.x * 256 + threadIdx.x;  // 0..65535
  int bg = idx >> 10;                        // global batch 0..63
  int k = idx & 1023;
  int g = bg >> 4, bl = bg & 15;
  float v = h0[idx];
  unsigned short hh = f2bf(v);
  unsigned short hl = f2bf(v - bf2f(hh));
  size_t base = ((size_t)(g * 2 + 0) * 2) * 16384 + (size_t)bl * 1024 + k;
  hex[base] = hh;            // hi plane
  hex[base + 16384] = hl;    // lo plane
  if (blockIdx.x == 0) flags[threadIdx.x] = 0u;  // 128 used, 256 zeroed
}

// ---------------------------------------------------------------------------
// pack W_ih [512][1024] fp32 -> B-fragment layout, hi/lo bf16 planes
// ---------------------------------------------------------------------------
__global__ __launch_bounds__(256) void rnn_pack_wih(const float* __restrict__ W_ih,
                                                    unsigned short* __restrict__ bhi,
                                                    unsigned short* __restrict__ blo) {
  int idx = blockIdx.x * 256 + threadIdx.x;  // 0..524287
  int j = idx & 7;
  int l = (idx >> 3) & 63;
  int kc = (idx >> 9) & 15;
  int nc = idx >> 13;
  int k = kc * 32 + ((l >> 4) << 3) + j;
  int n = nc * 16 + (l & 15);
  float v = W_ih[(size_t)k * D_H + n];
  unsigned short h = f2bf(v);
  bhi[idx] = h;
  blo[idx] = f2bf(v - bf2f(h));
}

// ---------------------------------------------------------------------------
// stage 1: xw[t*64+b][n] = embed[tokens[b][t]] @ W_ih + bias_hh   (bf16x3 MFMA)
// ---------------------------------------------------------------------------
__global__ __launch_bounds__(256) void rnn_stage1(const int* __restrict__ tokens,
                                                  const float* __restrict__ embed,
                                                  const unsigned short* __restrict__ bhi,
                                                  const unsigned short* __restrict__ blo,
                                                  const float* __restrict__ bias,
                                                  float* __restrict__ xw) {
  int bx = blockIdx.x;
  int mt = bx >> 4, nt = bx & 15;
  int tid = threadIdx.x;
  int w = tid >> 6, l = tid & 63;
  int q = l >> 4;

  int m = mt * 64 + w * 16 + (l & 15);  // A-operand row
  int b = m & 63, t = m >> 6;
  int tok = tokens[b * NS + t];
  const float* arow = embed + (size_t)tok * D_IN;

  f32x4 acc[4];
#pragma unroll
  for (int i = 0; i < 4; ++i) acc[i] = (f32x4){0.f, 0.f, 0.f, 0.f};

  for (int c = 0; c < 16; ++c) {
    const float* ap = arow + c * 32 + q * 8;
    float4 f0 = *(const float4*)ap;
    float4 f1 = *(const float4*)(ap + 4);
    float fa[8] = {f0.x, f0.y, f0.z, f0.w, f1.x, f1.y, f1.z, f1.w};
    short8 ahi, alo;
#pragma unroll
    for (int j = 0; j < 8; ++j) {
      unsigned short hh = f2bf(fa[j]);
      ahi[j] = (short)hh;
      alo[j] = (short)f2bf(fa[j] - bf2f(hh));
    }
#pragma unroll
    for (int ni = 0; ni < 4; ++ni) {
      int ncg = nt * 4 + ni;
      size_t boff = ((size_t)(ncg * 16 + c) * 64 + l) * 8;
      short8 bh = *(const short8*)(bhi + boff);
      short8 bl_ = *(const short8*)(blo + boff);
      acc[ni] = mfma_bf16(ahi, bh, acc[ni]);
      acc[ni] = mfma_bf16(alo, bh, acc[ni]);
      acc[ni] = mfma_bf16(ahi, bl_, acc[ni]);
    }
  }

#pragma unroll
  for (int ni = 0; ni < 4; ++ni) {
    int col = nt * 64 + ni * 16 + (l & 15);
    float bv = bias[col];
#pragma unroll
    for (int r = 0; r < 4; ++r) {
      int row = mt * 64 + w * 16 + q * 4 + r;  // D-layout row
      xw[(size_t)row * D_H + col] = acc[ni][r] + bv;
    }
  }
}

// ---------------------------------------------------------------------------
// stage 2: persistent recurrence. 128 WGs = 4 batch-groups x 32 j-tiles.
// Each WG owns 32 j-columns: W_hh slice (1024 x 32) in LDS as bf16 hi/lo
// (128 KB) in B-fragment order, 2 subtiles of 16 cols.
// Sync: 32 per-WG flag STORES (no RMW) packed in one 128B line; only wave 0
// polls (one coalesced request), other waves wait at the barrier.
// ---------------------------------------------------------------------------
__global__ __launch_bounds__(256, 1) void rnn_recur(const float* __restrict__ xw,
                                                    const float* __restrict__ W_hh,
                                                    unsigned short* __restrict__ hex,
                                                    unsigned int* __restrict__ flags,
                                                    float* __restrict__ h_last) {
  __shared__ short Whi[32768];        // 64 KB
  __shared__ short Wlo[32768];        // 64 KB
  __shared__ float red[4][16][33];    // 8448 B  (total 139520 B -> 1 WG/CU)

  const int tid = threadIdx.x;
  const int bx = blockIdx.x;
  const int g = bx >> 5;     // batch group 0..3
  const int jt = bx & 31;    // j tile 0..31
  const int jcol0 = jt * 32;
  const int w = tid >> 6;
  const int l = tid & 63;
  const int q = l >> 4;
  const int b_lane = l & 15;

  // one-time: load + split W_hh slice into LDS in B-fragment order.
  // v = ((s*32 + c)*64 + ll)*8 + j  ->  k = c*32+((ll>>4)<<3)+j, n = s*16+(ll&15)
  for (int v = tid; v < 32768; v += 256) {
    int j = v & 7;
    int ll = (v >> 3) & 63;
    int c = (v >> 9) & 31;
    int s = v >> 14;
    int k = c * 32 + ((ll >> 4) << 3) + j;
    int n = s * 16 + (ll & 15);
    float wv = W_hh[(size_t)k * D_H + jcol0 + n];
    unsigned short hh = f2bf(wv);
    Whi[v] = (short)hh;
    Wlo[v] = (short)f2bf(wv - bf2f(hh));
  }
  __syncthreads();

  unsigned int* flg = flags + g * 32;  // one 128B line per group

  // epilogue constants: 2 adjacent j per thread (packed dword stores)
  const int be = tid >> 4;            // batch 0..15
  const int je2 = (tid & 15) * 2;     // j 0,2,..,30
  const int brow = g * 16 + be;

  for (int t = 1; t <= NS; ++t) {
    // prefetch this step's xw pair (flag-independent; hides under poll)
    const float* xwp = xw + ((size_t)(t - 1) * 64 + brow) * D_H + jcol0 + je2;
    float xv0 = xwp[0];
    float xv1 = xwp[1];

    // wave 0 polls the group's 32 flags (one coalesced request per poll)
    if (tid < 64) {
      unsigned int target = (unsigned int)(t - 1);
      while (1) {
        unsigned int v = __hip_atomic_load(&flg[l & 31], __ATOMIC_RELAXED,
                                           __HIP_MEMORY_SCOPE_AGENT);
        if (__all((int)(v >= target))) break;
      }
    }
    __syncthreads();

    int rbuf = (t - 1) & 1;
    const unsigned long long* hhi =
        (const unsigned long long*)(hex + ((size_t)(g * 2 + rbuf) * 2 + 0) * 16384);
    const unsigned long long* hlo =
        (const unsigned long long*)(hex + ((size_t)(g * 2 + rbuf) * 2 + 1) * 16384);

    // ---- issue ALL h loads first (one pipelined LLC round) ----
    HQ ha[8], hl_[8];
#pragma unroll
    for (int i = 0; i < 8; ++i) {
      int c = w * 8 + i;
      int k = c * 32 + q * 8;
      size_t qi = ((size_t)b_lane * 1024 + k) >> 2;  // u64 index
      ha[i].q[0] = __hip_atomic_load(hhi + qi, __ATOMIC_RELAXED, __HIP_MEMORY_SCOPE_AGENT);
      ha[i].q[1] = __hip_atomic_load(hhi + qi + 1, __ATOMIC_RELAXED, __HIP_MEMORY_SCOPE_AGENT);
      hl_[i].q[0] = __hip_atomic_load(hlo + qi, __ATOMIC_RELAXED, __HIP_MEMORY_SCOPE_AGENT);
      hl_[i].q[1] = __hip_atomic_load(hlo + qi + 1, __ATOMIC_RELAXED, __HIP_MEMORY_SCOPE_AGENT);
    }

    // ---- MFMA chains, both 16-col subtiles ----
    f32x4 a00 = {0.f, 0.f, 0.f, 0.f}, a01 = a00, a02 = a00;
    f32x4 a10 = a00, a11 = a00, a12 = a00;
#pragma unroll
    for (int i = 0; i < 8; ++i) {
      int c = w * 8 + i;
      short8 bh0 = *(const short8*)(Whi + c * 512 + l * 8);
      short8 bl0 = *(const short8*)(Wlo + c * 512 + l * 8);
      short8 bh1 = *(const short8*)(Whi + 16384 + c * 512 + l * 8);
      short8 bl1 = *(const short8*)(Wlo + 16384 + c * 512 + l * 8);
      a00 = mfma_bf16(ha[i].s, bh0, a00);
      a01 = mfma_bf16(hl_[i].s, bh0, a01);
      a02 = mfma_bf16(ha[i].s, bl0, a02);
      a10 = mfma_bf16(ha[i].s, bh1, a10);
      a11 = mfma_bf16(hl_[i].s, bh1, a11);
      a12 = mfma_bf16(ha[i].s, bl1, a12);
    }
    f32x4 s0 = a00 + a01 + a02;
    f32x4 s1 = a10 + a11 + a12;
#pragma unroll
    for (int r = 0; r < 4; ++r) {
      red[w][q * 4 + r][b_lane] = s0[r];
      red[w][q * 4 + r][16 + b_lane] = s1[r];
    }
    __syncthreads();

    // ---- epilogue: every thread handles (be, je2) and (be, je2+1) ----
    float z0 = red[0][be][je2] + red[1][be][je2] + red[2][be][je2] +
               red[3][be][je2] + xv0;
    float z1 = red[0][be][je2 + 1] + red[1][be][je2 + 1] + red[2][be][je2 + 1] +
               red[3][be][je2 + 1] + xv1;
    float hv0 = tanhf(z0);
    float hv1 = tanhf(z1);
    unsigned short h0h = f2bf(hv0), h1h = f2bf(hv1);
    unsigned short h0l = f2bf(hv0 - bf2f(h0h)), h1l = f2bf(hv1 - bf2f(h1h));
    int wbuf = t & 1;
    size_t obase = (size_t)be * 1024 + jcol0 + je2;
    unsigned int* dhi =
        (unsigned int*)(hex + ((size_t)(g * 2 + wbuf) * 2 + 0) * 16384 + obase);
    unsigned int* dlo =
        (unsigned int*)(hex + ((size_t)(g * 2 + wbuf) * 2 + 1) * 16384 + obase);
    unsigned int phi = (unsigned int)h0h | ((unsigned int)h1h << 16);
    unsigned int plo = (unsigned int)h0l | ((unsigned int)h1l << 16);
    __hip_atomic_store(dhi, phi, __ATOMIC_RELAXED, __HIP_MEMORY_SCOPE_AGENT);
    __hip_atomic_store(dlo, plo, __ATOMIC_RELAXED, __HIP_MEMORY_SCOPE_AGENT);
    if (t == NS) {
      h_last[(size_t)brow * 1024 + jcol0 + je2] = hv0;
      h_last[(size_t)brow * 1024 + jcol0 + je2 + 1] = hv1;
    }

    // Release: drain each wave's sc1 write-through stores to the LLC, then
    // one plain flag STORE per WG (no RMW). Barrier also protects `red`.
    asm volatile("s_waitcnt vmcnt(0)" ::: "memory");
    __syncthreads();
    if (tid == 0)
      __hip_atomic_store(&flg[jt], (unsigned int)t, __ATOMIC_RELAXED,
                         __HIP_MEMORY_SCOPE_AGENT);
  }
}

// ---------------------------------------------------------------------------
// stage 3: y[b][j] = h_last[b][:] . W_out[:][j] + b_out[j]   (fp32 vector)
// ---------------------------------------------------------------------------
__global__ __launch_bounds__(256, 2) void rnn_out(const float* __restrict__ h_last,
                                                  const float* __restrict__ W_out,
                                                  const float* __restrict__ b_out,
                                                  float* __restrict__ out) {
  __shared__ float smem[16384];
  int tid = threadIdx.x;
  int jl = tid & 127;
  int kh = tid >> 7;
  int j = blockIdx.x * 128 + jl;

  float acc[64];
#pragma unroll
  for (int b = 0; b < 64; ++b) acc[b] = 0.f;

  for (int kc = 0; kc < 4; ++kc) {
    __syncthreads();
    for (int v = tid; v < 16384; v += 256) {
      int kh2 = v >> 13;
      int b = (v >> 7) & 63;
      int kk = v & 127;
      smem[v] = h_last[(size_t)b * 1024 + kh2 * 512 + kc * 128 + kk];
    }
    __syncthreads();
    int kbase = kh * 512 + kc * 128;
    for (int kkc = 0; kkc < 16; ++kkc) {
      float wreg[8];
#pragma unroll
      for (int i = 0; i < 8; ++i)
        wreg[i] = W_out[(size_t)(kbase + kkc * 8 + i) * D_OUT + j];
#pragma unroll
      for (int b = 0; b < 64; ++b) {
        const float* hp = &smem[kh * 8192 + b * 128 + kkc * 8];
#pragma unroll
        for (int i = 0; i < 8; ++i) acc[b] += hp[i] * wreg[i];
      }
    }
  }
  __syncthreads();
  if (kh == 1) {
#pragma unroll
    for (int b = 0; b < 64; ++b) smem[jl * 65 + b] = acc[b];
  }
  __syncthreads();
  if (kh == 0) {
    float bo = b_out[j];
#pragma unroll
    for (int b = 0; b < 64; ++b)
      out[(size_t)b * D_OUT + j] = acc[b] + smem[jl * 65 + b] + bo;
  }
}

// ---------------------------------------------------------------------------
extern "C" void kernel_launch(void* const* d_in, const int* in_sizes, int n_in,
                              void* d_out, int out_size, void* d_ws, size_t ws_size,
                              hipStream_t stream) {
  const int* tokens = (const int*)d_in[0];
  const float* h0 = (const float*)d_in[1];
  const float* embed = (const float*)d_in[2];
  const float* W_ih = (const float*)d_in[3];
  const float* W_hh = (const float*)d_in[4];
  const float* bias_hh = (const float*)d_in[5];
  const float* W_out = (const float*)d_in[6];
  const float* b_out = (const float*)d_in[7];
  float* out = (float*)d_out;

  char* ws = (char*)d_ws;
  // workspace layout (bytes)
  float* xw = (float*)(ws);                                   // 134217728
  unsigned short* wih_hi = (unsigned short*)(ws + 134217728); // 1048576
  unsigned short* wih_lo = (unsigned short*)(ws + 135266304); // 1048576
  unsigned short* hex = (unsigned short*)(ws + 136314880);    // 524288
  unsigned int* flags = (unsigned int*)(ws + 136839168);      // 1024
  float* h_last = (float*)(ws + 136840192);                   // 262144
  // total: 137102336 bytes

  rnn_init<<<256, 256, 0, stream>>>(h0, hex, flags);
  rnn_pack_wih<<<2048, 256, 0, stream>>>(W_ih, wih_hi, wih_lo);
  rnn_stage1<<<8192, 256, 0, stream>>>(tokens, embed, wih_hi, wih_lo, bias_hh, xw);
  rnn_recur<<<128, 256, 0, stream>>>(xw, W_hh, hex, flags, h_last);
  rnn_out<<<250, 256, 0, stream>>>(h_last, W_out, b_out, out);
}